// Round 12
// baseline (229.470 us; speedup 1.0000x reference)
//
#include <hip/hip_runtime.h>
#include <hip/hip_fp16.h>
#include <math.h>

#define N_NODES 100000
#define N_EDGES 1600000
#define IN_DIM 256
#define OUT_DIM 64

// ---- bucketed fused sort+aggregate ----
#define NB 512                   // buckets
#define RPB 196                  // rows per bucket; 512*196 = 100352 >= N_NODES
#define BCAP 3712                // per-bucket capacity (mean 3136, +10 sd)
#define CAP 17                   // per-bucket LDS slots; ODD stride -> bank (17b+p)&31 spreads (16 was 8-bank clustered)
#define CHUNK_E 4096             // edges per bin block
#define NBIN_BLK ((N_EDGES + CHUNK_E - 1) / CHUNK_E)  // 391
#define NGEMM_BLK ((N_NODES + 255) / 256)             // 391 (256 rows/block @ 8 waves x 2 tiles)

// ---- workspace layout (bytes); bp lives until aggregate -> no aliasing ----
#define X_OFF         0UL          // 12,800,000 B: x[N_NODES][64] fp16
#define BP_OFF        12800000UL   // 7,602,176 B: int bp[NB][BCAP]
#define WIMG_OFF      20500000UL   // 65,536 B: weight image (16B-aligned)
#define BCUR_OFF      20600000UL   // 2,048 B: int bcur[NB]
// total ~20.6 MB

typedef short bf16x8 __attribute__((ext_vector_type(8)));
typedef float f32x4 __attribute__((ext_vector_type(4)));

// ---------------- Weight -> bf16 hi/lo B-fragment image (64 KB) + bcur zero ----------------
__global__ __launch_bounds__(256) void convert_weight(const float* __restrict__ w,
                                                      ushort* __restrict__ img,
                                                      int* __restrict__ bcur) {
    const int g = blockIdx.x * 256 + threadIdx.x;  // 0..16383
    if (g < NB) bcur[g] = 0;                       // replaces hipMemsetAsync (runs before bin)
    const int j = g & 7, l = (g >> 3) & 63, ts = g >> 9;  // ts = t*8+s
    const int s = ts & 7, t = ts >> 3;
    const int k = s * 32 + (l >> 4) * 8 + j;
    const int c = t * 16 + (l & 15);
    const float v = w[k * OUT_DIM + c];
    const unsigned b = __float_as_uint(v);
    const float r = v - __uint_as_float(b & 0xFFFF0000u);  // residual after hi-truncation
    img[(ts * 2 + 0) * 512 + l * 8 + j] = (ushort)(b >> 16);
    img[(ts * 2 + 1) * 512 + l * 8 + j] = (ushort)(__float_as_uint(r) >> 16);
}

// ---------------- GEMM body (role A, 512 threads, 2 row-tiles/wave) ----------------
// LDS-staged weight image; per B-fragment ds_read pair -> 6 MFMAs (2 tiles) instead
// of 3: halves the LDS-read count per MFMA (the wave's critical path). 256 rows/block.
__device__ __forceinline__ void gemm_body(char* smem, int bid,
                                          const float* __restrict__ inputs,
                                          const ushort* __restrict__ wimg,
                                          __half* __restrict__ x) {
    ushort* lds = (ushort*)smem;  // 64 KB
    const int tid = threadIdx.x;  // 0..511

    #pragma unroll
    for (int i = 0; i < 8; ++i) {
        const int c = tid + i * 512;  // 16B-chunk index 0..4095
        *(int4*)(lds + c * 8) = *(const int4*)(wimg + c * 8);
    }
    __syncthreads();

    const int wv = tid >> 6, l = tid & 63;       // wv 0..7
    const int rbase = bid * 256 + wv * 32;       // two 16-row tiles: rbase, rbase+16
    const int koff = (l >> 4) * 8;

    bf16x8 ah[2][8], al[2][8];
    #pragma unroll
    for (int m = 0; m < 2; ++m) {
        const int arow_idx = rbase + m * 16 + (l & 15);
        const int row_c = arow_idx < N_NODES ? arow_idx : N_NODES - 1;  // clamp loads
        const float* arow = inputs + (size_t)row_c * IN_DIM;
        #pragma unroll
        for (int s = 0; s < 8; ++s) {
            const float4 p = *(const float4*)(arow + s * 32 + koff);
            const float4 q = *(const float4*)(arow + s * 32 + koff + 4);
            const float v[8] = {p.x, p.y, p.z, p.w, q.x, q.y, q.z, q.w};
            #pragma unroll
            for (int j = 0; j < 8; ++j) {
                const unsigned bb = __float_as_uint(v[j]);
                const float r = v[j] - __uint_as_float(bb & 0xFFFF0000u);
                ah[m][s][j] = (short)(bb >> 16);
                al[m][s][j] = (short)(__float_as_uint(r) >> 16);
            }
        }
    }

    f32x4 acc[2][4];
    #pragma unroll
    for (int m = 0; m < 2; ++m)
        #pragma unroll
        for (int t = 0; t < 4; ++t) acc[m][t] = (f32x4){0.f, 0.f, 0.f, 0.f};

    const bf16x8* b8 = (const bf16x8*)lds;
    #pragma unroll
    for (int t = 0; t < 4; ++t) {
        #pragma unroll
        for (int s = 0; s < 8; ++s) {
            const bf16x8 bh = b8[((t * 8 + s) * 2 + 0) * 64 + l];
            const bf16x8 blo = b8[((t * 8 + s) * 2 + 1) * 64 + l];
            #pragma unroll
            for (int m = 0; m < 2; ++m) {
                acc[m][t] = __builtin_amdgcn_mfma_f32_16x16x32_bf16(ah[m][s], bh, acc[m][t], 0, 0, 0);
                acc[m][t] = __builtin_amdgcn_mfma_f32_16x16x32_bf16(al[m][s], bh, acc[m][t], 0, 0, 0);
                acc[m][t] = __builtin_amdgcn_mfma_f32_16x16x32_bf16(ah[m][s], blo, acc[m][t], 0, 0, 0);
            }
        }
    }

    #pragma unroll
    for (int m = 0; m < 2; ++m) {
        const int mbase = rbase + m * 16 + (l >> 4) * 4;
        #pragma unroll
        for (int reg = 0; reg < 4; ++reg) {
            const int row = mbase + reg;
            if (row < N_NODES) {
                #pragma unroll
                for (int t = 0; t < 4; ++t)
                    x[(size_t)row * OUT_DIM + t * 16 + (l & 15)] = __float2half(acc[m][t][reg]);
            }
        }
    }
}

// ---------------- Bin body (role B of fused kernel, 512 threads) ----------------
// pack = (rloc << 17) | col, rloc = r - bucket*RPB (<196 -> 9 bits), col < 2^17.
// CAP=17 (odd stride): lbuf bank = (17b+p)&31 -> spreads over random b; flush reads
// hit consecutive banks. LDS 40,960 B.
__device__ __forceinline__ void bin_body(char* smem, int bid,
                                         const int* __restrict__ rows,
                                         const int* __restrict__ cols,
                                         int* __restrict__ bcur,
                                         int* __restrict__ bp) {
    int* lbuf  = (int*)smem;                  // 34,816 B (512*17*4)
    int* lcnt  = (int*)(smem + NB * CAP * 4); // 2,048 B
    int* ltot  = lcnt + NB;
    int* lbase = ltot + NB;                   // total 40,960 B
    const int tid = threadIdx.x;  // 0..511 == NB
    lcnt[tid] = 0;
    __syncthreads();

    const int base = bid * CHUNK_E;
    #pragma unroll
    for (int g = 0; g < 2; ++g) {
        const int e = base + (g * 512 + tid) * 4;
        if (e < N_EDGES) {  // N_EDGES % 4 == 0, whole int4 in range
            const int4 r4 = *(const int4*)(rows + e);
            const int4 c4 = *(const int4*)(cols + e);
            const int rr[4] = {r4.x, r4.y, r4.z, r4.w};
            const int cc[4] = {c4.x, c4.y, c4.z, c4.w};
            #pragma unroll
            for (int u = 0; u < 4; ++u) {
                const int r = rr[u];
                const int b = r / RPB;                       // const div -> magic mul
                const int pack = ((r - b * RPB) << 17) | cc[u];
                const int p = atomicAdd(&lcnt[b], 1);
                if (p < CAP) {
                    lbuf[b * CAP + p] = pack;
                } else {  // rare spill (guarded against BCAP overflow)
                    const int gp = atomicAdd(&bcur[b], 1);
                    if (gp < BCAP) bp[b * BCAP + gp] = pack;
                }
            }
        }
    }
    __syncthreads();
    {
        const int tot = min(lcnt[tid], CAP);
        ltot[tid] = tot;
        lbase[tid] = atomicAdd(&bcur[tid], tot);
    }
    __syncthreads();
    // flush: 16-lane group per bucket; i strides 16 (2nd pass covers slot 16)
    #pragma unroll
    for (int k = 0; k < 16; ++k) {
        const int b = (k << 5) + (tid >> 4);
        const int tot = ltot[b];
        const int gb = lbase[b];
        for (int i = tid & 15; i < tot; i += 16) {
            const int gp = gb + i;
            if (gp < BCAP) bp[b * BCAP + gp] = lbuf[b * CAP + i];  // guard vs overflow
        }
    }
}

// ---------------- Fused bin + GEMM (interleaved roles, one launch, 512 thr) ----------------
// Roles interleaved by blockIdx&1 so each CU hosts BOTH latency-bound bin waves and
// MFMA-bound gemm waves (dispatch-order segregation serialized the phases before).
__global__ __launch_bounds__(512) void fused_gemm_bin(const float* __restrict__ inputs,
                                                      const ushort* __restrict__ wimg,
                                                      __half* __restrict__ x,
                                                      const int* __restrict__ rows,
                                                      const int* __restrict__ cols,
                                                      int* __restrict__ bcur,
                                                      int* __restrict__ bp) {
    __shared__ __align__(16) char smem[65536];  // union: gemm 64KB / bin 40.9KB
    const int bid = blockIdx.x;                 // 0..781
    if ((bid & 1) == 0)
        bin_body(smem, bid >> 1, rows, cols, bcur, bp);   // evens: 391 bin blocks
    else
        gemm_body(smem, bid >> 1, inputs, wimg, x);       // odds: 391 gemm blocks
}

// ---------------- Fused LDS sort + pull-aggregate + sigmoid (1024 threads) ----------------
// One block per bucket, 16 waves -> 2 blocks/CU = 32 waves/CU, all 512 blocks
// co-resident. Phases 1-3 row-group packs in LDS. Phase 4: wave = 8 edge-slots x
// 8 lanes, TWO rows in flight per wave (8 outstanding uint4 gathers/lane).
__global__ __launch_bounds__(1024) void aggregate_kernel(const int* __restrict__ bp,
                                                         const int* __restrict__ bcur,
                                                         const __half* __restrict__ x,
                                                         float* __restrict__ out) {
    __shared__ int ebuf[BCAP];       // 14,848 B staged packs
    __shared__ int sbuf[BCAP];       // 14,848 B row-grouped cols
    __shared__ int hist[RPB];
    __shared__ int roff[RPB + 1];
    __shared__ int cur[RPB];
    __shared__ int sc[256], sc2[256];
    const int b = blockIdx.x, t = threadIdx.x;  // t in [0,1024)
    const int n = min(bcur[b], BCAP);   // defensive clamp (overflow statistically never)
    const int* bb = bp + b * BCAP;

    if (t < RPB) hist[t] = 0;
    __syncthreads();

    // Phase 1: stage + LDS histogram (int4-vectorized global reads)
    const int4* bb4 = (const int4*)bb;
    for (int i = t; i * 4 + 3 < n; i += 1024) {
        const int4 v = bb4[i];
        *(int4*)(ebuf + i * 4) = v;
        atomicAdd(&hist[v.x >> 17], 1);
        atomicAdd(&hist[v.y >> 17], 1);
        atomicAdd(&hist[v.z >> 17], 1);
        atomicAdd(&hist[v.w >> 17], 1);
    }
    {   // scalar tail (< 4 packs)
        const int i = (n & ~3) + t;
        if (i < n) {
            const int v = bb[i];
            ebuf[i] = v;
            atomicAdd(&hist[v >> 17], 1);
        }
    }
    __syncthreads();

    // Phase 2: exclusive scan of hist -> row offsets + cursors (first 256 threads
    // do the work; ALL threads hit every barrier)
    if (t < 256) sc[t] = (t < RPB) ? hist[t] : 0;
    __syncthreads();
    int* src = sc; int* dst = sc2;
    for (int off = 1; off < 256; off <<= 1) {
        if (t < 256) dst[t] = src[t] + ((t >= off) ? src[t - off] : 0);
        __syncthreads();
        int* tmp = src; src = dst; dst = tmp;
    }
    if (t < RPB) { const int e = src[t] - hist[t]; roff[t] = e; cur[t] = e; }
    if (t == 0) roff[RPB] = n;
    __syncthreads();

    // Phase 3: place (LDS cursor atomics, LDS -> LDS)
    for (int i = t; i < n; i += 1024) {
        const int v = ebuf[i];
        const int p = atomicAdd(&cur[v >> 17], 1);
        sbuf[p] = v & 0x1FFFF;
    }
    __syncthreads();

    // Phase 4: pull-aggregate, row-PAIR per wave. Wave w: rows (2w, 2w+1), +32...
    const int w = t >> 6, lane = t & 63;
    const int g = lane >> 3;       // edge slot 0..7
    const int s = lane & 7;        // column slice: cols 8s..8s+7 (16B)
    const __half* xs = x + s * 8;

    for (int rl0 = w * 2; rl0 < RPB; rl0 += 32) {
        const int row0 = b * RPB + rl0;
        if (row0 >= N_NODES) break;        // wave-uniform (row1 also out)
        const int rl1 = rl0 + 1;           // RPB even -> rl1 < RPB
        const int row1 = row0 + 1;
        const int end0 = roff[rl0 + 1];
        const int end1 = roff[rl1 + 1];
        int j0 = roff[rl0], j1 = roff[rl1];

        float a0[8], a1[8];
        #pragma unroll
        for (int q = 0; q < 8; ++q) { a0[q] = 0.f; a1[q] = 0.f; }

        while (j0 < end0 || j1 < end1) {   // 32+32 edges per pass, 8 loads/lane in flight
            #pragma unroll
            for (int u = 0; u < 4; ++u) {
                const int ej = j0 + u * 8 + g;
                if (ej < end0) {
                    const int cc = sbuf[ej];
                    const uint4 d = *(const uint4*)(xs + (size_t)cc * OUT_DIM);
                    const __half2* h2 = (const __half2*)&d;
                    #pragma unroll
                    for (int q = 0; q < 4; ++q) {
                        const float2 f = __half22float2(h2[q]);
                        a0[2 * q] += f.x; a0[2 * q + 1] += f.y;
                    }
                }
            }
            #pragma unroll
            for (int u = 0; u < 4; ++u) {
                const int ej = j1 + u * 8 + g;
                if (ej < end1) {
                    const int cc = sbuf[ej];
                    const uint4 d = *(const uint4*)(xs + (size_t)cc * OUT_DIM);
                    const __half2* h2 = (const __half2*)&d;
                    #pragma unroll
                    for (int q = 0; q < 4; ++q) {
                        const float2 f = __half22float2(h2[q]);
                        a1[2 * q] += f.x; a1[2 * q + 1] += f.y;
                    }
                }
            }
            j0 += 32; j1 += 32;
        }

        // combine the 8 edge-slots (lane bits 3,4,5); afterwards ALL lanes hold totals
        #pragma unroll
        for (int q = 0; q < 8; ++q) {
            a0[q] += __shfl_xor(a0[q], 8);
            a0[q] += __shfl_xor(a0[q], 16);
            a0[q] += __shfl_xor(a0[q], 32);
            a1[q] += __shfl_xor(a1[q], 8);
            a1[q] += __shfl_xor(a1[q], 16);
            a1[q] += __shfl_xor(a1[q], 32);
        }

        if (lane < 8) {                       // lanes 0-7 store row0
            float4 o0, o1;
            o0.x = 1.f / (1.f + __expf(-a0[0]));
            o0.y = 1.f / (1.f + __expf(-a0[1]));
            o0.z = 1.f / (1.f + __expf(-a0[2]));
            o0.w = 1.f / (1.f + __expf(-a0[3]));
            o1.x = 1.f / (1.f + __expf(-a0[4]));
            o1.y = 1.f / (1.f + __expf(-a0[5]));
            o1.z = 1.f / (1.f + __expf(-a0[6]));
            o1.w = 1.f / (1.f + __expf(-a0[7]));
            float* op = out + (size_t)row0 * OUT_DIM + s * 8;
            *(float4*)op = o0;
            *(float4*)(op + 4) = o1;
        } else if (lane < 16 && row1 < N_NODES) {  // lanes 8-15 store row1
            float4 o0, o1;
            o0.x = 1.f / (1.f + __expf(-a1[0]));
            o0.y = 1.f / (1.f + __expf(-a1[1]));
            o0.z = 1.f / (1.f + __expf(-a1[2]));
            o0.w = 1.f / (1.f + __expf(-a1[3]));
            o1.x = 1.f / (1.f + __expf(-a1[4]));
            o1.y = 1.f / (1.f + __expf(-a1[5]));
            o1.z = 1.f / (1.f + __expf(-a1[6]));
            o1.w = 1.f / (1.f + __expf(-a1[7]));
            float* op = out + (size_t)row1 * OUT_DIM + s * 8;
            *(float4*)op = o0;
            *(float4*)(op + 4) = o1;
        }
    }
}

extern "C" void kernel_launch(void* const* d_in, const int* in_sizes, int n_in,
                              void* d_out, int out_size, void* d_ws, size_t ws_size,
                              hipStream_t stream) {
    const float* inputs = (const float*)d_in[0];
    const int* edge_index = (const int*)d_in[1];  // [2, N_EDGES], int32 on device
    const float* weight = (const float*)d_in[2];
    float* out = (float*)d_out;

    char* ws = (char*)d_ws;
    __half* x        = (__half*)(ws + X_OFF);
    int* bp          = (int*)(ws + BP_OFF);
    ushort* wimg     = (ushort*)(ws + WIMG_OFF);
    int* bcur        = (int*)(ws + BCUR_OFF);

    const int* rows = edge_index;
    const int* cols = edge_index + N_EDGES;

    // convert zeroes bcur + builds wimg (ordered before fused kernel on the stream)
    convert_weight<<<64, 256, 0, stream>>>(weight, wimg, bcur);
    fused_gemm_bin<<<NBIN_BLK + NGEMM_BLK, 512, 0, stream>>>(inputs, wimg, x,
                                                             rows, cols, bcur, bp);
    aggregate_kernel<<<NB, 1024, 0, stream>>>(bp, bcur, x, out);
}

// Round 13
// 227.053 us; speedup vs baseline: 1.0106x; 1.0106x over previous
//
#include <hip/hip_runtime.h>
#include <hip/hip_fp16.h>
#include <math.h>

#define N_NODES 100000
#define N_EDGES 1600000
#define IN_DIM 256
#define OUT_DIM 64

// ---- bucketed fused sort+aggregate ----
#define NB 512                   // buckets
#define RPB 196                  // rows per bucket; 512*196 = 100352 >= N_NODES
#define BCAP 3712                // per-bucket capacity (mean 3136, +10 sd)
#define CAP 16                   // per-bucket LDS staging slots in bin (round-11 proven)
#define CHUNK_E 4096             // edges per bin block
#define NBIN_BLK ((N_EDGES + CHUNK_E - 1) / CHUNK_E)  // 391
#define NGEMM_BLK ((N_NODES + 255) / 256)             // 391 (256 rows/block @ 8 waves x 2 tiles)

// ---- workspace layout (bytes); bp lives until aggregate -> no aliasing ----
#define X_OFF         0UL          // 12,800,000 B: x[N_NODES][64] fp16
#define BP_OFF        12800000UL   // 7,602,176 B: int bp[NB][BCAP]
#define BCUR_OFF      20600000UL   // 2,048 B: int bcur[NB]
// total ~20.6 MB

typedef short bf16x8 __attribute__((ext_vector_type(8)));
typedef float f32x4 __attribute__((ext_vector_type(4)));

// ---------------- GEMM body (role A, 512 threads, 2 row-tiles/wave) ----------------
// Weight converted fp32->bf16 hi/lo image DIRECTLY into LDS (weight is 64KB,
// L2-resident after block 0) — deletes the separate convert_weight dispatch.
// Then: per B-fragment ds_read pair -> 6 MFMAs (2 row-tiles). 256 rows/block.
__device__ __forceinline__ void gemm_body(char* smem, int bid,
                                          const float* __restrict__ inputs,
                                          const float* __restrict__ w,
                                          __half* __restrict__ x) {
    ushort* lds = (ushort*)smem;  // 64 KB image
    const int tid = threadIdx.x;  // 0..511

    // Inline weight conversion: image chunk ts*2+h (1KB each), lane l, elem j.
    #pragma unroll
    for (int i = 0; i < 32; ++i) {
        const int g = tid + i * 512;            // 0..16383
        const int j = g & 7, l = (g >> 3) & 63, ts = g >> 9;  // ts = t*8+s
        const int s = ts & 7, t = ts >> 3;
        const int k = s * 32 + (l >> 4) * 8 + j;
        const int c = t * 16 + (l & 15);
        const float v = w[k * OUT_DIM + c];
        const unsigned bb = __float_as_uint(v);
        const float r = v - __uint_as_float(bb & 0xFFFF0000u);  // residual after hi-truncation
        lds[(ts * 2 + 0) * 512 + l * 8 + j] = (ushort)(bb >> 16);
        lds[(ts * 2 + 1) * 512 + l * 8 + j] = (ushort)(__float_as_uint(r) >> 16);
    }
    __syncthreads();

    const int wv = tid >> 6, l = tid & 63;       // wv 0..7
    const int rbase = bid * 256 + wv * 32;       // two 16-row tiles: rbase, rbase+16
    const int koff = (l >> 4) * 8;

    bf16x8 ah[2][8], al[2][8];
    #pragma unroll
    for (int m = 0; m < 2; ++m) {
        const int arow_idx = rbase + m * 16 + (l & 15);
        const int row_c = arow_idx < N_NODES ? arow_idx : N_NODES - 1;  // clamp loads
        const float* arow = inputs + (size_t)row_c * IN_DIM;
        #pragma unroll
        for (int s = 0; s < 8; ++s) {
            const float4 p = *(const float4*)(arow + s * 32 + koff);
            const float4 q = *(const float4*)(arow + s * 32 + koff + 4);
            const float v[8] = {p.x, p.y, p.z, p.w, q.x, q.y, q.z, q.w};
            #pragma unroll
            for (int j = 0; j < 8; ++j) {
                const unsigned bb = __float_as_uint(v[j]);
                const float r = v[j] - __uint_as_float(bb & 0xFFFF0000u);
                ah[m][s][j] = (short)(bb >> 16);
                al[m][s][j] = (short)(__float_as_uint(r) >> 16);
            }
        }
    }

    f32x4 acc[2][4];
    #pragma unroll
    for (int m = 0; m < 2; ++m)
        #pragma unroll
        for (int t = 0; t < 4; ++t) acc[m][t] = (f32x4){0.f, 0.f, 0.f, 0.f};

    const bf16x8* b8 = (const bf16x8*)lds;
    #pragma unroll
    for (int t = 0; t < 4; ++t) {
        #pragma unroll
        for (int s = 0; s < 8; ++s) {
            const bf16x8 bh = b8[((t * 8 + s) * 2 + 0) * 64 + l];
            const bf16x8 blo = b8[((t * 8 + s) * 2 + 1) * 64 + l];
            #pragma unroll
            for (int m = 0; m < 2; ++m) {
                acc[m][t] = __builtin_amdgcn_mfma_f32_16x16x32_bf16(ah[m][s], bh, acc[m][t], 0, 0, 0);
                acc[m][t] = __builtin_amdgcn_mfma_f32_16x16x32_bf16(al[m][s], bh, acc[m][t], 0, 0, 0);
                acc[m][t] = __builtin_amdgcn_mfma_f32_16x16x32_bf16(ah[m][s], blo, acc[m][t], 0, 0, 0);
            }
        }
    }

    #pragma unroll
    for (int m = 0; m < 2; ++m) {
        const int mbase = rbase + m * 16 + (l >> 4) * 4;
        #pragma unroll
        for (int reg = 0; reg < 4; ++reg) {
            const int row = mbase + reg;
            if (row < N_NODES) {
                #pragma unroll
                for (int t = 0; t < 4; ++t)
                    x[(size_t)row * OUT_DIM + t * 16 + (l & 15)] = __float2half(acc[m][t][reg]);
            }
        }
    }
}

// ---------------- Bin body (role B of fused kernel, 512 threads) ----------------
// pack = (rloc << 17) | col, rloc = r - bucket*RPB (<196 -> 9 bits), col < 2^17.
// CAP=16, lambda=8: spill fraction ~0.4% via guarded global path. LDS 38.9 KB.
__device__ __forceinline__ void bin_body(char* smem, int bid,
                                         const int* __restrict__ rows,
                                         const int* __restrict__ cols,
                                         int* __restrict__ bcur,
                                         int* __restrict__ bp) {
    int* lbuf  = (int*)smem;                  // 32,768 B
    int* lcnt  = (int*)(smem + NB * CAP * 4); // 2,048 B
    int* ltot  = lcnt + NB;
    int* lbase = ltot + NB;                   // total 38,912 B
    const int tid = threadIdx.x;  // 0..511 == NB
    lcnt[tid] = 0;
    __syncthreads();

    const int base = bid * CHUNK_E;
    #pragma unroll
    for (int g = 0; g < 2; ++g) {
        const int e = base + (g * 512 + tid) * 4;
        if (e < N_EDGES) {  // N_EDGES % 4 == 0, whole int4 in range
            const int4 r4 = *(const int4*)(rows + e);
            const int4 c4 = *(const int4*)(cols + e);
            const int rr[4] = {r4.x, r4.y, r4.z, r4.w};
            const int cc[4] = {c4.x, c4.y, c4.z, c4.w};
            #pragma unroll
            for (int u = 0; u < 4; ++u) {
                const int r = rr[u];
                const int b = r / RPB;                       // const div -> magic mul
                const int pack = ((r - b * RPB) << 17) | cc[u];
                const int p = atomicAdd(&lcnt[b], 1);
                if (p < CAP) {
                    lbuf[b * CAP + p] = pack;
                } else {  // rare spill (guarded against BCAP overflow)
                    const int gp = atomicAdd(&bcur[b], 1);
                    if (gp < BCAP) bp[b * BCAP + gp] = pack;
                }
            }
        }
    }
    __syncthreads();
    {
        const int tot = min(lcnt[tid], CAP);
        ltot[tid] = tot;
        lbase[tid] = atomicAdd(&bcur[tid], tot);
    }
    __syncthreads();
    // flush: 16-lane group per bucket (CAP=16) -> coalesced packed stores
    #pragma unroll
    for (int k = 0; k < 16; ++k) {
        const int b = (k << 5) + (tid >> 4);
        const int i = tid & 15;
        if (i < ltot[b]) {
            const int gp = lbase[b] + i;
            if (gp < BCAP) bp[b * BCAP + gp] = lbuf[b * CAP + i];  // guard vs overflow
        }
    }
}

// ---------------- Fused bin + GEMM (segregated roles — round-11 proven) ----------------
// Blocks 0..390 bin, 391..781 gemm. Segregation keeps each CU's LDS dedicated to
// one role (interleaving measured -8 µs: both roles are LDS-bandwidth-heavy).
__global__ __launch_bounds__(512) void fused_gemm_bin(const float* __restrict__ inputs,
                                                      const float* __restrict__ weight,
                                                      __half* __restrict__ x,
                                                      const int* __restrict__ rows,
                                                      const int* __restrict__ cols,
                                                      int* __restrict__ bcur,
                                                      int* __restrict__ bp) {
    __shared__ __align__(16) char smem[65536];  // union: gemm 64KB / bin 38.9KB
    if (blockIdx.x < NBIN_BLK)
        bin_body(smem, blockIdx.x, rows, cols, bcur, bp);
    else
        gemm_body(smem, blockIdx.x - NBIN_BLK, inputs, weight, x);
}

// ---------------- Fused LDS sort + pull-aggregate + sigmoid (1024 threads) ----------------
// One block per bucket, 16 waves -> 2 blocks/CU = 32 waves/CU, all 512 blocks
// co-resident. Phases 1-3 row-group packs in LDS. Phase 4: wave = 8 edge-slots x
// 8 lanes, TWO rows in flight per wave (8 outstanding uint4 gathers/lane).
__global__ __launch_bounds__(1024) void aggregate_kernel(const int* __restrict__ bp,
                                                         const int* __restrict__ bcur,
                                                         const __half* __restrict__ x,
                                                         float* __restrict__ out) {
    __shared__ int ebuf[BCAP];       // 14,848 B staged packs
    __shared__ int sbuf[BCAP];       // 14,848 B row-grouped cols
    __shared__ int hist[RPB];
    __shared__ int roff[RPB + 1];
    __shared__ int cur[RPB];
    __shared__ int sc[256], sc2[256];
    const int b = blockIdx.x, t = threadIdx.x;  // t in [0,1024)
    const int n = min(bcur[b], BCAP);   // defensive clamp (overflow statistically never)
    const int* bb = bp + b * BCAP;

    if (t < RPB) hist[t] = 0;
    __syncthreads();

    // Phase 1: stage + LDS histogram (int4-vectorized global reads)
    const int4* bb4 = (const int4*)bb;
    for (int i = t; i * 4 + 3 < n; i += 1024) {
        const int4 v = bb4[i];
        *(int4*)(ebuf + i * 4) = v;
        atomicAdd(&hist[v.x >> 17], 1);
        atomicAdd(&hist[v.y >> 17], 1);
        atomicAdd(&hist[v.z >> 17], 1);
        atomicAdd(&hist[v.w >> 17], 1);
    }
    {   // scalar tail (< 4 packs)
        const int i = (n & ~3) + t;
        if (i < n) {
            const int v = bb[i];
            ebuf[i] = v;
            atomicAdd(&hist[v >> 17], 1);
        }
    }
    __syncthreads();

    // Phase 2: exclusive scan of hist -> row offsets + cursors (first 256 threads
    // do the work; ALL threads hit every barrier)
    if (t < 256) sc[t] = (t < RPB) ? hist[t] : 0;
    __syncthreads();
    int* src = sc; int* dst = sc2;
    for (int off = 1; off < 256; off <<= 1) {
        if (t < 256) dst[t] = src[t] + ((t >= off) ? src[t - off] : 0);
        __syncthreads();
        int* tmp = src; src = dst; dst = tmp;
    }
    if (t < RPB) { const int e = src[t] - hist[t]; roff[t] = e; cur[t] = e; }
    if (t == 0) roff[RPB] = n;
    __syncthreads();

    // Phase 3: place (LDS cursor atomics, LDS -> LDS)
    for (int i = t; i < n; i += 1024) {
        const int v = ebuf[i];
        const int p = atomicAdd(&cur[v >> 17], 1);
        sbuf[p] = v & 0x1FFFF;
    }
    __syncthreads();

    // Phase 4: pull-aggregate, row-PAIR per wave. Wave w: rows (2w, 2w+1), +32...
    const int w = t >> 6, lane = t & 63;
    const int g = lane >> 3;       // edge slot 0..7
    const int s = lane & 7;        // column slice: cols 8s..8s+7 (16B)
    const __half* xs = x + s * 8;

    for (int rl0 = w * 2; rl0 < RPB; rl0 += 32) {
        const int row0 = b * RPB + rl0;
        if (row0 >= N_NODES) break;        // wave-uniform (row1 also out)
        const int rl1 = rl0 + 1;           // RPB even -> rl1 < RPB
        const int row1 = row0 + 1;
        const int end0 = roff[rl0 + 1];
        const int end1 = roff[rl1 + 1];
        int j0 = roff[rl0], j1 = roff[rl1];

        float a0[8], a1[8];
        #pragma unroll
        for (int q = 0; q < 8; ++q) { a0[q] = 0.f; a1[q] = 0.f; }

        while (j0 < end0 || j1 < end1) {   // 32+32 edges per pass, 8 loads/lane in flight
            #pragma unroll
            for (int u = 0; u < 4; ++u) {
                const int ej = j0 + u * 8 + g;
                if (ej < end0) {
                    const int cc = sbuf[ej];
                    const uint4 d = *(const uint4*)(xs + (size_t)cc * OUT_DIM);
                    const __half2* h2 = (const __half2*)&d;
                    #pragma unroll
                    for (int q = 0; q < 4; ++q) {
                        const float2 f = __half22float2(h2[q]);
                        a0[2 * q] += f.x; a0[2 * q + 1] += f.y;
                    }
                }
            }
            #pragma unroll
            for (int u = 0; u < 4; ++u) {
                const int ej = j1 + u * 8 + g;
                if (ej < end1) {
                    const int cc = sbuf[ej];
                    const uint4 d = *(const uint4*)(xs + (size_t)cc * OUT_DIM);
                    const __half2* h2 = (const __half2*)&d;
                    #pragma unroll
                    for (int q = 0; q < 4; ++q) {
                        const float2 f = __half22float2(h2[q]);
                        a1[2 * q] += f.x; a1[2 * q + 1] += f.y;
                    }
                }
            }
            j0 += 32; j1 += 32;
        }

        // combine the 8 edge-slots (lane bits 3,4,5); afterwards ALL lanes hold totals
        #pragma unroll
        for (int q = 0; q < 8; ++q) {
            a0[q] += __shfl_xor(a0[q], 8);
            a0[q] += __shfl_xor(a0[q], 16);
            a0[q] += __shfl_xor(a0[q], 32);
            a1[q] += __shfl_xor(a1[q], 8);
            a1[q] += __shfl_xor(a1[q], 16);
            a1[q] += __shfl_xor(a1[q], 32);
        }

        if (lane < 8) {                       // lanes 0-7 store row0
            float4 o0, o1;
            o0.x = 1.f / (1.f + __expf(-a0[0]));
            o0.y = 1.f / (1.f + __expf(-a0[1]));
            o0.z = 1.f / (1.f + __expf(-a0[2]));
            o0.w = 1.f / (1.f + __expf(-a0[3]));
            o1.x = 1.f / (1.f + __expf(-a0[4]));
            o1.y = 1.f / (1.f + __expf(-a0[5]));
            o1.z = 1.f / (1.f + __expf(-a0[6]));
            o1.w = 1.f / (1.f + __expf(-a0[7]));
            float* op = out + (size_t)row0 * OUT_DIM + s * 8;
            *(float4*)op = o0;
            *(float4*)(op + 4) = o1;
        } else if (lane < 16 && row1 < N_NODES) {  // lanes 8-15 store row1
            float4 o0, o1;
            o0.x = 1.f / (1.f + __expf(-a1[0]));
            o0.y = 1.f / (1.f + __expf(-a1[1]));
            o0.z = 1.f / (1.f + __expf(-a1[2]));
            o0.w = 1.f / (1.f + __expf(-a1[3]));
            o1.x = 1.f / (1.f + __expf(-a1[4]));
            o1.y = 1.f / (1.f + __expf(-a1[5]));
            o1.z = 1.f / (1.f + __expf(-a1[6]));
            o1.w = 1.f / (1.f + __expf(-a1[7]));
            float* op = out + (size_t)row1 * OUT_DIM + s * 8;
            *(float4*)op = o0;
            *(float4*)(op + 4) = o1;
        }
    }
}

extern "C" void kernel_launch(void* const* d_in, const int* in_sizes, int n_in,
                              void* d_out, int out_size, void* d_ws, size_t ws_size,
                              hipStream_t stream) {
    const float* inputs = (const float*)d_in[0];
    const int* edge_index = (const int*)d_in[1];  // [2, N_EDGES], int32 on device
    const float* weight = (const float*)d_in[2];
    float* out = (float*)d_out;

    char* ws = (char*)d_ws;
    __half* x        = (__half*)(ws + X_OFF);
    int* bp          = (int*)(ws + BP_OFF);
    int* bcur        = (int*)(ws + BCUR_OFF);

    const int* rows = edge_index;
    const int* cols = edge_index + N_EDGES;

    hipMemsetAsync(bcur, 0, NB * sizeof(int), stream);
    fused_gemm_bin<<<NBIN_BLK + NGEMM_BLK, 512, 0, stream>>>(inputs, weight, x,
                                                             rows, cols, bcur, bp);
    aggregate_kernel<<<NB, 1024, 0, stream>>>(bp, bcur, x, out);
}

// Round 14
// 220.522 us; speedup vs baseline: 1.0406x; 1.0296x over previous
//
#include <hip/hip_runtime.h>
#include <hip/hip_fp16.h>
#include <math.h>

#define N_NODES 100000
#define N_EDGES 1600000
#define IN_DIM 256
#define OUT_DIM 64

// ---- bucketed fused sort+aggregate ----
#define NB 512                   // buckets
#define RPB 196                  // rows per bucket; 512*196 = 100352 >= N_NODES
#define BCAP 3712                // per-bucket capacity (mean 3136, +10 sd)
#define CAP 16                   // per-bucket LDS staging slots in bin (mean 8; tail spills guarded)
#define CHUNK_E 4096             // edges per bin block
#define NBIN_BLK ((N_EDGES + CHUNK_E - 1) / CHUNK_E)  // 391
#define NGEMM_BLK ((N_NODES + 255) / 256)             // 391 (256 rows/block @ 8 waves x 2 tiles)

// ---- workspace layout (bytes); bp lives until aggregate -> no aliasing ----
#define X_OFF         0UL          // 12,800,000 B: x[N_NODES][64] fp16
#define BP_OFF        12800000UL   // 7,602,176 B: int bp[NB][BCAP]
#define WIMG_OFF      20500000UL   // 65,536 B: weight image (16B-aligned)
#define BCUR_OFF      20600000UL   // 2,048 B: int bcur[NB]
// total ~20.6 MB

typedef short bf16x8 __attribute__((ext_vector_type(8)));
typedef float f32x4 __attribute__((ext_vector_type(4)));

// ---------------- Weight -> bf16 hi/lo B-fragment image (64 KB) + bcur zero ----------------
__global__ __launch_bounds__(256) void convert_weight(const float* __restrict__ w,
                                                      ushort* __restrict__ img,
                                                      int* __restrict__ bcur) {
    const int g = blockIdx.x * 256 + threadIdx.x;  // 0..16383
    if (g < NB) bcur[g] = 0;                       // replaces hipMemsetAsync (runs before bin)
    const int j = g & 7, l = (g >> 3) & 63, ts = g >> 9;  // ts = t*8+s
    const int s = ts & 7, t = ts >> 3;
    const int k = s * 32 + (l >> 4) * 8 + j;
    const int c = t * 16 + (l & 15);
    const float v = w[k * OUT_DIM + c];
    const unsigned b = __float_as_uint(v);
    const float r = v - __uint_as_float(b & 0xFFFF0000u);  // residual after hi-truncation
    img[(ts * 2 + 0) * 512 + l * 8 + j] = (ushort)(b >> 16);
    img[(ts * 2 + 1) * 512 + l * 8 + j] = (ushort)(__float_as_uint(r) >> 16);
}

// ---------------- GEMM body (role A, 512 threads, 2 row-tiles/wave) ----------------
// LDS-staged weight image; per B-fragment ds_read pair -> 6 MFMAs (2 tiles) instead
// of 3: halves the LDS-read count per MFMA (the wave's critical path). 256 rows/block.
__device__ __forceinline__ void gemm_body(char* smem, int bid,
                                          const float* __restrict__ inputs,
                                          const ushort* __restrict__ wimg,
                                          __half* __restrict__ x) {
    ushort* lds = (ushort*)smem;  // 64 KB
    const int tid = threadIdx.x;  // 0..511

    #pragma unroll
    for (int i = 0; i < 8; ++i) {
        const int c = tid + i * 512;  // 16B-chunk index 0..4095
        *(int4*)(lds + c * 8) = *(const int4*)(wimg + c * 8);
    }
    __syncthreads();

    const int wv = tid >> 6, l = tid & 63;       // wv 0..7
    const int rbase = bid * 256 + wv * 32;       // two 16-row tiles: rbase, rbase+16
    const int koff = (l >> 4) * 8;

    bf16x8 ah[2][8], al[2][8];
    #pragma unroll
    for (int m = 0; m < 2; ++m) {
        const int arow_idx = rbase + m * 16 + (l & 15);
        const int row_c = arow_idx < N_NODES ? arow_idx : N_NODES - 1;  // clamp loads
        const float* arow = inputs + (size_t)row_c * IN_DIM;
        #pragma unroll
        for (int s = 0; s < 8; ++s) {
            const float4 p = *(const float4*)(arow + s * 32 + koff);
            const float4 q = *(const float4*)(arow + s * 32 + koff + 4);
            const float v[8] = {p.x, p.y, p.z, p.w, q.x, q.y, q.z, q.w};
            #pragma unroll
            for (int j = 0; j < 8; ++j) {
                const unsigned bb = __float_as_uint(v[j]);
                const float r = v[j] - __uint_as_float(bb & 0xFFFF0000u);
                ah[m][s][j] = (short)(bb >> 16);
                al[m][s][j] = (short)(__float_as_uint(r) >> 16);
            }
        }
    }

    f32x4 acc[2][4];
    #pragma unroll
    for (int m = 0; m < 2; ++m)
        #pragma unroll
        for (int t = 0; t < 4; ++t) acc[m][t] = (f32x4){0.f, 0.f, 0.f, 0.f};

    const bf16x8* b8 = (const bf16x8*)lds;
    #pragma unroll
    for (int t = 0; t < 4; ++t) {
        #pragma unroll
        for (int s = 0; s < 8; ++s) {
            const bf16x8 bh = b8[((t * 8 + s) * 2 + 0) * 64 + l];
            const bf16x8 blo = b8[((t * 8 + s) * 2 + 1) * 64 + l];
            #pragma unroll
            for (int m = 0; m < 2; ++m) {
                acc[m][t] = __builtin_amdgcn_mfma_f32_16x16x32_bf16(ah[m][s], bh, acc[m][t], 0, 0, 0);
                acc[m][t] = __builtin_amdgcn_mfma_f32_16x16x32_bf16(al[m][s], bh, acc[m][t], 0, 0, 0);
                acc[m][t] = __builtin_amdgcn_mfma_f32_16x16x32_bf16(ah[m][s], blo, acc[m][t], 0, 0, 0);
            }
        }
    }

    #pragma unroll
    for (int m = 0; m < 2; ++m) {
        const int mbase = rbase + m * 16 + (l >> 4) * 4;
        #pragma unroll
        for (int reg = 0; reg < 4; ++reg) {
            const int row = mbase + reg;
            if (row < N_NODES) {
                #pragma unroll
                for (int t = 0; t < 4; ++t)
                    x[(size_t)row * OUT_DIM + t * 16 + (l & 15)] = __float2half(acc[m][t][reg]);
            }
        }
    }
}

// ---------------- Bin body (role B of fused kernel, 512 threads) ----------------
// pack = (rloc << 17) | col, rloc = r - bucket*RPB (<196 -> 9 bits), col < 2^17.
// CAP=16, lambda=8: spill fraction ~0.4% via guarded global path. LDS 38.9 KB.
__device__ __forceinline__ void bin_body(char* smem, int bid,
                                         const int* __restrict__ rows,
                                         const int* __restrict__ cols,
                                         int* __restrict__ bcur,
                                         int* __restrict__ bp) {
    int* lbuf  = (int*)smem;                  // 32,768 B
    int* lcnt  = (int*)(smem + NB * CAP * 4); // 2,048 B
    int* ltot  = lcnt + NB;
    int* lbase = ltot + NB;                   // total 38,912 B
    const int tid = threadIdx.x;  // 0..511 == NB
    lcnt[tid] = 0;
    __syncthreads();

    const int base = bid * CHUNK_E;
    #pragma unroll
    for (int g = 0; g < 2; ++g) {
        const int e = base + (g * 512 + tid) * 4;
        if (e < N_EDGES) {  // N_EDGES % 4 == 0, whole int4 in range
            const int4 r4 = *(const int4*)(rows + e);
            const int4 c4 = *(const int4*)(cols + e);
            const int rr[4] = {r4.x, r4.y, r4.z, r4.w};
            const int cc[4] = {c4.x, c4.y, c4.z, c4.w};
            #pragma unroll
            for (int u = 0; u < 4; ++u) {
                const int r = rr[u];
                const int b = r / RPB;                       // const div -> magic mul
                const int pack = ((r - b * RPB) << 17) | cc[u];
                const int p = atomicAdd(&lcnt[b], 1);
                if (p < CAP) {
                    lbuf[b * CAP + p] = pack;
                } else {  // rare spill (guarded against BCAP overflow)
                    const int gp = atomicAdd(&bcur[b], 1);
                    if (gp < BCAP) bp[b * BCAP + gp] = pack;
                }
            }
        }
    }
    __syncthreads();
    {
        const int tot = min(lcnt[tid], CAP);
        ltot[tid] = tot;
        lbase[tid] = atomicAdd(&bcur[tid], tot);
    }
    __syncthreads();
    // flush: 16-lane group per bucket (CAP=16) -> coalesced packed stores
    #pragma unroll
    for (int k = 0; k < 16; ++k) {
        const int b = (k << 5) + (tid >> 4);
        const int i = tid & 15;
        if (i < ltot[b]) {
            const int gp = lbase[b] + i;
            if (gp < BCAP) bp[b * BCAP + gp] = lbuf[b * CAP + i];  // guard vs overflow
        }
    }
}

// ---------------- Fused bin + GEMM (segregated roles, one launch, 512 thr) ----------------
// Blocks 0..390 bin, 391..781 gemm. Segregation keeps each CU's LDS dedicated to one
// role (interleaving measured -8 µs: both roles are LDS-bandwidth-heavy). 64KB union
// LDS -> 2 blocks/CU x 8 waves = 16 waves/CU = the VGPR(~68) ceiling.
__global__ __launch_bounds__(512) void fused_gemm_bin(const float* __restrict__ inputs,
                                                      const ushort* __restrict__ wimg,
                                                      __half* __restrict__ x,
                                                      const int* __restrict__ rows,
                                                      const int* __restrict__ cols,
                                                      int* __restrict__ bcur,
                                                      int* __restrict__ bp) {
    __shared__ __align__(16) char smem[65536];  // union: gemm 64KB / bin 38.9KB
    if (blockIdx.x < NBIN_BLK)
        bin_body(smem, blockIdx.x, rows, cols, bcur, bp);
    else
        gemm_body(smem, blockIdx.x - NBIN_BLK, inputs, wimg, x);
}

// ---------------- Fused LDS sort + pull-aggregate + sigmoid (1024 threads) ----------------
// One block per bucket, 16 waves -> 2 blocks/CU = 32 waves/CU, all 512 blocks
// co-resident. Phases 1-3 row-group packs in LDS. Phase 4: wave = 8 edge-slots x
// 8 lanes, TWO rows in flight per wave (8 outstanding uint4 gathers/lane).
__global__ __launch_bounds__(1024) void aggregate_kernel(const int* __restrict__ bp,
                                                         const int* __restrict__ bcur,
                                                         const __half* __restrict__ x,
                                                         float* __restrict__ out) {
    __shared__ int ebuf[BCAP];       // 14,848 B staged packs
    __shared__ int sbuf[BCAP];       // 14,848 B row-grouped cols
    __shared__ int hist[RPB];
    __shared__ int roff[RPB + 1];
    __shared__ int cur[RPB];
    __shared__ int sc[256], sc2[256];
    const int b = blockIdx.x, t = threadIdx.x;  // t in [0,1024)
    const int n = min(bcur[b], BCAP);   // defensive clamp (overflow statistically never)
    const int* bb = bp + b * BCAP;

    if (t < RPB) hist[t] = 0;
    __syncthreads();

    // Phase 1: stage + LDS histogram (int4-vectorized global reads)
    const int4* bb4 = (const int4*)bb;
    for (int i = t; i * 4 + 3 < n; i += 1024) {
        const int4 v = bb4[i];
        *(int4*)(ebuf + i * 4) = v;
        atomicAdd(&hist[v.x >> 17], 1);
        atomicAdd(&hist[v.y >> 17], 1);
        atomicAdd(&hist[v.z >> 17], 1);
        atomicAdd(&hist[v.w >> 17], 1);
    }
    {   // scalar tail (< 4 packs)
        const int i = (n & ~3) + t;
        if (i < n) {
            const int v = bb[i];
            ebuf[i] = v;
            atomicAdd(&hist[v >> 17], 1);
        }
    }
    __syncthreads();

    // Phase 2: exclusive scan of hist -> row offsets + cursors (first 256 threads
    // do the work; ALL threads hit every barrier)
    if (t < 256) sc[t] = (t < RPB) ? hist[t] : 0;
    __syncthreads();
    int* src = sc; int* dst = sc2;
    for (int off = 1; off < 256; off <<= 1) {
        if (t < 256) dst[t] = src[t] + ((t >= off) ? src[t - off] : 0);
        __syncthreads();
        int* tmp = src; src = dst; dst = tmp;
    }
    if (t < RPB) { const int e = src[t] - hist[t]; roff[t] = e; cur[t] = e; }
    if (t == 0) roff[RPB] = n;
    __syncthreads();

    // Phase 3: place (LDS cursor atomics, LDS -> LDS)
    for (int i = t; i < n; i += 1024) {
        const int v = ebuf[i];
        const int p = atomicAdd(&cur[v >> 17], 1);
        sbuf[p] = v & 0x1FFFF;
    }
    __syncthreads();

    // Phase 4: pull-aggregate, row-PAIR per wave. Wave w: rows (2w, 2w+1), +32...
    const int w = t >> 6, lane = t & 63;
    const int g = lane >> 3;       // edge slot 0..7
    const int s = lane & 7;        // column slice: cols 8s..8s+7 (16B)
    const __half* xs = x + s * 8;

    for (int rl0 = w * 2; rl0 < RPB; rl0 += 32) {
        const int row0 = b * RPB + rl0;
        if (row0 >= N_NODES) break;        // wave-uniform (row1 also out)
        const int rl1 = rl0 + 1;           // RPB even -> rl1 < RPB
        const int row1 = row0 + 1;
        const int end0 = roff[rl0 + 1];
        const int end1 = roff[rl1 + 1];
        int j0 = roff[rl0], j1 = roff[rl1];

        float a0[8], a1[8];
        #pragma unroll
        for (int q = 0; q < 8; ++q) { a0[q] = 0.f; a1[q] = 0.f; }

        while (j0 < end0 || j1 < end1) {   // 32+32 edges per pass, 8 loads/lane in flight
            #pragma unroll
            for (int u = 0; u < 4; ++u) {
                const int ej = j0 + u * 8 + g;
                if (ej < end0) {
                    const int cc = sbuf[ej];
                    const uint4 d = *(const uint4*)(xs + (size_t)cc * OUT_DIM);
                    const __half2* h2 = (const __half2*)&d;
                    #pragma unroll
                    for (int q = 0; q < 4; ++q) {
                        const float2 f = __half22float2(h2[q]);
                        a0[2 * q] += f.x; a0[2 * q + 1] += f.y;
                    }
                }
            }
            #pragma unroll
            for (int u = 0; u < 4; ++u) {
                const int ej = j1 + u * 8 + g;
                if (ej < end1) {
                    const int cc = sbuf[ej];
                    const uint4 d = *(const uint4*)(xs + (size_t)cc * OUT_DIM);
                    const __half2* h2 = (const __half2*)&d;
                    #pragma unroll
                    for (int q = 0; q < 4; ++q) {
                        const float2 f = __half22float2(h2[q]);
                        a1[2 * q] += f.x; a1[2 * q + 1] += f.y;
                    }
                }
            }
            j0 += 32; j1 += 32;
        }

        // combine the 8 edge-slots (lane bits 3,4,5); afterwards ALL lanes hold totals
        #pragma unroll
        for (int q = 0; q < 8; ++q) {
            a0[q] += __shfl_xor(a0[q], 8);
            a0[q] += __shfl_xor(a0[q], 16);
            a0[q] += __shfl_xor(a0[q], 32);
            a1[q] += __shfl_xor(a1[q], 8);
            a1[q] += __shfl_xor(a1[q], 16);
            a1[q] += __shfl_xor(a1[q], 32);
        }

        if (lane < 8) {                       // lanes 0-7 store row0
            float4 o0, o1;
            o0.x = 1.f / (1.f + __expf(-a0[0]));
            o0.y = 1.f / (1.f + __expf(-a0[1]));
            o0.z = 1.f / (1.f + __expf(-a0[2]));
            o0.w = 1.f / (1.f + __expf(-a0[3]));
            o1.x = 1.f / (1.f + __expf(-a0[4]));
            o1.y = 1.f / (1.f + __expf(-a0[5]));
            o1.z = 1.f / (1.f + __expf(-a0[6]));
            o1.w = 1.f / (1.f + __expf(-a0[7]));
            float* op = out + (size_t)row0 * OUT_DIM + s * 8;
            *(float4*)op = o0;
            *(float4*)(op + 4) = o1;
        } else if (lane < 16 && row1 < N_NODES) {  // lanes 8-15 store row1
            float4 o0, o1;
            o0.x = 1.f / (1.f + __expf(-a1[0]));
            o0.y = 1.f / (1.f + __expf(-a1[1]));
            o0.z = 1.f / (1.f + __expf(-a1[2]));
            o0.w = 1.f / (1.f + __expf(-a1[3]));
            o1.x = 1.f / (1.f + __expf(-a1[4]));
            o1.y = 1.f / (1.f + __expf(-a1[5]));
            o1.z = 1.f / (1.f + __expf(-a1[6]));
            o1.w = 1.f / (1.f + __expf(-a1[7]));
            float* op = out + (size_t)row1 * OUT_DIM + s * 8;
            *(float4*)op = o0;
            *(float4*)(op + 4) = o1;
        }
    }
}

extern "C" void kernel_launch(void* const* d_in, const int* in_sizes, int n_in,
                              void* d_out, int out_size, void* d_ws, size_t ws_size,
                              hipStream_t stream) {
    const float* inputs = (const float*)d_in[0];
    const int* edge_index = (const int*)d_in[1];  // [2, N_EDGES], int32 on device
    const float* weight = (const float*)d_in[2];
    float* out = (float*)d_out;

    char* ws = (char*)d_ws;
    __half* x        = (__half*)(ws + X_OFF);
    int* bp          = (int*)(ws + BP_OFF);
    ushort* wimg     = (ushort*)(ws + WIMG_OFF);
    int* bcur        = (int*)(ws + BCUR_OFF);

    const int* rows = edge_index;
    const int* cols = edge_index + N_EDGES;

    // convert zeroes bcur + builds wimg (ordered before fused kernel on the stream)
    convert_weight<<<64, 256, 0, stream>>>(weight, wimg, bcur);
    fused_gemm_bin<<<NBIN_BLK + NGEMM_BLK, 512, 0, stream>>>(inputs, wimg, x,
                                                             rows, cols, bcur, bp);
    aggregate_kernel<<<NB, 1024, 0, stream>>>(bp, bcur, x, out);
}